// Round 20
// baseline (2921.031 us; speedup 1.0000x reference)
//
#include <hip/hip_runtime.h>
#include <math.h>

// ---------------- problem constants ----------------
constexpr int BB   = 4;
constexpr int TT   = 400;
constexpr int FF   = 1025;
constexpr int NFFT = 2048;
constexpr int HOP  = 512;
constexpr int PADD = 1024;
constexpr int LL   = HOP * (TT - 1);        // 204288
constexpr int LPAD = NFFT + HOP * (TT - 1); // 206336
constexpr int NITER = 60;
constexpr double MOM = 0.99 / 1.99;
constexpr double EPSV = 1e-16;
constexpr double DPI = 3.14159265358979323846;

// workspace offsets in DOUBLES (all even -> 16B alignment)
constexpr size_t OFF_TW1024 = 0;          // 1024 double2 = 2048 d
constexpr size_t OFF_TW2048 = 2048;       // 1025 double2 = 2050 d
constexpr size_t OFF_FRM    = 4098;       // B*T*2048 = 3276800 d
constexpr size_t OFF_XP0    = 3280898;    // B*LPAD = 825344 d
constexpr size_t OFF_XP1    = 4106242;    // B*LPAD = 825344 d
constexpr size_t OFF_WIN32  = 4931586;    // f32 window: 2048 f = 1024 d
constexpr size_t OFF_WSQ32  = 4932610;    // f32 wsq: 206336 f = 103168 d
constexpr size_t WS_DOUBLES = 5035778;    // ~40.3 MB

__device__ __forceinline__ double2 cmuld(double2 a, double2 b) {
    return make_double2(a.x * b.x - a.y * b.y, a.x * b.y + a.y * b.x);
}

// LDS layout swizzle (pure permutation of storage slots; injective on [0,1024))
__device__ __forceinline__ int swz(int f) { return f ^ ((f >> 4) & 7); }

// ---------------- numpy SIMD float32 cosine, bit-exact replica ----------------
__device__ __forceinline__ float np_cosf(float x) {
    const float rint_cvt = 0x1.800000p+23f;  // 12582912.0f
    float qf = __builtin_fmaf(x, 0x1.45f306p-1f, rint_cvt) - rint_cvt;
    float r = __builtin_fmaf(qf, -0x1.921fb0p+0f, x);
    r = __builtin_fmaf(qf, -0x1.5110b4p-22f, r);
    r = __builtin_fmaf(qf, -0x1.846988p-48f, r);
    r = __builtin_fmaf(qf, -0x1.8cc966p-73f, r);
    int q = (int)qf + 1;  // cos(x) = sin(x + pi/2)
    float r2 = r * r;
    float cosp = __builtin_fmaf(0x1.98e616p-16f, r2, -0x1.6c06dcp-10f);
    cosp = __builtin_fmaf(cosp, r2, 0x1.55553cp-5f);
    cosp = __builtin_fmaf(cosp, r2, -0x1.000000p-1f);
    cosp = __builtin_fmaf(cosp, r2, 0x1.000000p+0f);
    float sinp = __builtin_fmaf(0x1.7d3bbcp-19f, r2, -0x1.a06bbap-13f);
    sinp = __builtin_fmaf(sinp, r2, 0x1.11119ap-7f);
    sinp = __builtin_fmaf(sinp, r2, -0x1.555548p-3f);
    sinp = sinp * r2;
    sinp = __builtin_fmaf(sinp, r, r);
    float res = (q & 1) ? cosp : sinp;
    return (q & 2) ? -res : res;
}

// ---------------- init kernels ----------------
__global__ void k_init_tables(double2* tw1024, double2* tw2048, float* win) {
    int n = blockIdx.x * blockDim.x + threadIdx.x;
    if (n < 1024) {
        double th = -2.0 * DPI * (double)n / 1024.0;
        double s, c; sincos(th, &s, &c);
        tw1024[n] = make_double2(c, s);
    }
    if (n < 1025) {
        double th = -2.0 * DPI * (double)n / 2048.0;
        double s, c; sincos(th, &s, &c);
        tw2048[n] = make_double2(c, s);
    }
    if (n < 2048) {
        const float TWO_PI_F = 6.283185307179586f;
        float ang = __fdiv_rn(__fmul_rn(TWO_PI_F, (float)n), 2048.0f);
        float c = np_cosf(ang);
        win[n] = __fsub_rn(0.5f, __fmul_rn(0.5f, c));
    }
}

__global__ void k_init_wsq(const float* __restrict__ win, float* __restrict__ wsq) {
    int m = blockIdx.x * blockDim.x + threadIdx.x;
    if (m >= LPAD) return;
    int tlo = (m - (NFFT - HOP)) >> 9;
    if (tlo < 0) tlo = 0;
    int thi = m >> 9;
    if (thi > TT - 1) thi = TT - 1;
    float s = 0.0f;
    for (int t = tlo; t <= thi; ++t) {
        float w = win[m - (t << 9)];
        s = __fadd_rn(s, __fmul_rn(w, w));
    }
    wsq[m] = (s > 1e-11f) ? s : 1.0f;
}

// ---------------- radix-4 butterfly (expression-identical to R10) ----------------
template <int DIR, bool TW>
__device__ __forceinline__ void bfly4(double2 a, double2 b, double2 c, double2 d,
                                      double2 w1, double2 w2, double2 w3,
                                      double2& o0, double2& o1, double2& o2, double2& o3) {
    if (TW) {
        if (DIR > 0) { w1.y = -w1.y; w2.y = -w2.y; w3.y = -w3.y; }
        b = cmuld(b, w1);
        c = cmuld(c, w2);
        d = cmuld(d, w3);
    }
    double2 u0 = make_double2(a.x + c.x, a.y + c.y);
    double2 u1 = make_double2(a.x - c.x, a.y - c.y);
    double2 v0 = make_double2(b.x + d.x, b.y + d.y);
    double2 v1 = make_double2(b.x - d.x, b.y - d.y);
    o0 = make_double2(u0.x + v0.x, u0.y + v0.y);
    o2 = make_double2(u0.x - v0.x, u0.y - v0.y);
    if (DIR < 0) {
        o1 = make_double2(u1.x + v1.y, u1.y - v1.x);
        o3 = make_double2(u1.x - v1.y, u1.y + v1.x);
    } else {
        o1 = make_double2(u1.x - v1.y, u1.y + v1.x);
        o3 = make_double2(u1.x + v1.y, u1.y - v1.x);
    }
}

// ---------------- 1024-pt FFT, same radix-4 Stockham DAG, register-fused ----------------
// In: r[j] = x[tid + 64*j]. Out: r[j] = X[tid + 64*j]. 64 threads (one wave).
template <int DIR>
__device__ void fft1024_reg(double2 r[16], double2* S, const double2* __restrict__ tw, int tid) {
    const double2 wid = make_double2(1.0, 0.0);
    double2 e[4][4];
#pragma unroll
    for (int m = 0; m < 4; ++m)
        bfly4<DIR, false>(r[m], r[m + 4], r[m + 8], r[m + 12], wid, wid, wid,
                          e[m][0], e[m][1], e[m][2], e[m][3]);
    double2 g[4][4];
#pragma unroll
    for (int r1 = 0; r1 < 4; ++r1) {
        int t1 = r1 << 6;
        bfly4<DIR, true>(e[0][r1], e[1][r1], e[2][r1], e[3][r1],
                         tw[t1 & 1023], tw[(2 * t1) & 1023], tw[(3 * t1) & 1023],
                         g[r1][0], g[r1][1], g[r1][2], g[r1][3]);
    }
#pragma unroll
    for (int r1 = 0; r1 < 4; ++r1)
#pragma unroll
        for (int u = 0; u < 4; ++u)
            S[swz(16 * tid + r1 + 4 * u)] = g[r1][u];
    __syncthreads();
    double2 r2[16];
#pragma unroll
    for (int j = 0; j < 16; ++j) r2[j] = S[swz(tid + 64 * j)];
    const int kapp = tid & 15;
    const int aa = tid >> 4;
    double2 h[4][4];
    {
        int t = kapp << 4;
        double2 w1 = tw[t & 1023], w2 = tw[(2 * t) & 1023], w3 = tw[(3 * t) & 1023];
#pragma unroll
        for (int m = 0; m < 4; ++m)
            bfly4<DIR, true>(r2[m], r2[m + 4], r2[m + 8], r2[m + 12], w1, w2, w3,
                             h[m][0], h[m][1], h[m][2], h[m][3]);
    }
    double2 gg[4][4];
#pragma unroll
    for (int u = 0; u < 4; ++u) {
        int t = (kapp + 16 * u) << 2;
        bfly4<DIR, true>(h[0][u], h[1][u], h[2][u], h[3][u],
                         tw[t & 1023], tw[(2 * t) & 1023], tw[(3 * t) & 1023],
                         gg[u][0], gg[u][1], gg[u][2], gg[u][3]);
    }
#pragma unroll
    for (int u = 0; u < 4; ++u)
#pragma unroll
        for (int w = 0; w < 4; ++w)
            S[swz(256 * aa + kapp + 16 * u + 64 * w)] = gg[u][w];
    __syncthreads();
    double2 r4[16];
#pragma unroll
    for (int j = 0; j < 16; ++j) r4[j] = S[swz(tid + 64 * j)];
#pragma unroll
    for (int m = 0; m < 4; ++m) {
        int t = tid + 64 * m;
        bfly4<DIR, true>(r4[m], r4[m + 4], r4[m + 8], r4[m + 12],
                         tw[t & 1023], tw[(2 * t) & 1023], tw[(3 * t) & 1023],
                         r[m], r[m + 4], r[m + 8], r[m + 12]);
    }
}

// untwist only: Xk from (zk, zc, w) — the Xk lines of the original phase_step
__device__ __forceinline__ double2 untw(double2 zk, double2 zc, double2 w) {
    zc.y = -zc.y;
    double2 A = make_double2(0.5 * (zk.x + zc.x), 0.5 * (zk.y + zc.y));
    double2 D = make_double2(zk.x - zc.x, zk.y - zc.y);
    double2 Bv = make_double2(0.5 * D.y, -0.5 * D.x);  // -i*D/2
    double2 wB = cmuld(w, Bv);
    return make_double2(A.x + wB.x, A.y + wB.y);
}

// momentum + normalize + magnitude (remaining lines of original phase_step)
__device__ __forceinline__ double2 mom_phase(double2 Xk, double2 tp, float mgf) {
    double2 a = make_double2(Xk.x - MOM * tp.x, Xk.y - MOM * tp.y);
    double r = sqrt(a.x * a.x + a.y * a.y);
    double d = r + EPSV;
    double m = (double)mgf;
    return make_double2(m * (a.x / d), m * (a.y / d));
}

// pre-twist producing Z[k] from X[k], X[1024-k] (expression-identical)
__device__ __forceinline__ double2 pretwist(double2 Xk, double2 Xc, double2 w) {
    Xc.y = -Xc.y;
    double2 A = make_double2(0.5 * (Xk.x + Xc.x), 0.5 * (Xk.y + Xc.y));
    double2 D = make_double2(0.5 * (Xk.x - Xc.x), 0.5 * (Xk.y - Xc.y));
    w.y = -w.y;  // conj
    double2 Bv = cmuld(w, D);
    return make_double2(A.x - Bv.y, A.y + Bv.x);  // A + i*B
}

// ---------------- staged in-place FFT (k_istft_first only, runs once) ----------------
template <int DIR>
__device__ void fft1024_w(double2* buf, const double2* __restrict__ tw, int tid) {
#pragma unroll
    for (int s = 0; s < 5; ++s) {
        const int p = 1 << (2 * s);
        double2 o0[4], o1[4], o2[4], o3[4];
        int jj[4];
#pragma unroll
        for (int q = 0; q < 4; ++q) {
            int v = tid + 64 * q;
            int k = v & (p - 1);
            jj[q] = ((v - k) << 2) + k;
            int t1 = k << (8 - 2 * s);
            bfly4<DIR, true>(buf[v], buf[v + 256], buf[v + 512], buf[v + 768],
                             tw[t1 & 1023], tw[(2 * t1) & 1023], tw[(3 * t1) & 1023],
                             o0[q], o1[q], o2[q], o3[q]);
        }
        __syncthreads();
#pragma unroll
        for (int q = 0; q < 4; ++q) {
            buf[jj[q]]         = o0[q];
            buf[jj[q] + p]     = o1[q];
            buf[jj[q] + 2 * p] = o2[q];
            buf[jj[q] + 3 * p] = o3[q];
        }
        __syncthreads();
    }
}

// ---------------- initial frames: istft of (mag, 0), 64-thread ----------------
__global__ __launch_bounds__(64) void k_istft_first(
    const float* __restrict__ mag,
    const double2* __restrict__ tw1024, const double2* __restrict__ tw2048,
    const float* __restrict__ win, double* __restrict__ frames_out) {
    __shared__ double2 S[1025];
    const int fid = blockIdx.x;
    const int tid = threadIdx.x;
    const float* mg = mag + (size_t)fid * FF;
#pragma unroll
    for (int q = 0; q < 8; ++q) {
        int k = tid + 64 * q;  // [0,512)
        double mk = (double)mg[k];
        if (k == 0) {
            double m1024 = (double)mg[1024];
            double m512  = (double)mg[512];
            S[0]   = pretwist(make_double2(mk, 0.0),   make_double2(m1024, 0.0), tw2048[0]);
            S[512] = pretwist(make_double2(m512, 0.0), make_double2(m512, 0.0),  tw2048[512]);
        } else {
            int kp = 1024 - k;
            double mp = (double)mg[kp];
            S[k]  = pretwist(make_double2(mk, 0.0), make_double2(mp, 0.0), tw2048[k]);
            S[kp] = pretwist(make_double2(mp, 0.0), make_double2(mk, 0.0), tw2048[kp]);
        }
    }
    __syncthreads();
    fft1024_w<1>(S, tw1024, tid);
    double2* fr = reinterpret_cast<double2*>(frames_out + (size_t)fid * NFFT);
    const float2* w2 = reinterpret_cast<const float2*>(win);
#pragma unroll
    for (int q = 0; q < 16; ++q) {
        int m = tid + 64 * q;
        double2 z = S[m];
        float2 wv = w2[m];
        fr[m] = make_double2(z.x * (1.0 / 1024.0) * (double)wv.x,
                             z.y * (1.0 / 1024.0) * (double)wv.y);
    }
}

// ---------------- OLA: frames -> normalized reflect-padded signal xp ----------------
__global__ __launch_bounds__(256) void k_ola(
    const double* __restrict__ frames, const float* __restrict__ wsq,
    double* __restrict__ xp) {
    int bx = blockIdx.x;
    int bid = (bx & 7) * 403 + (bx >> 3);       // XCD swizzle, bijective (3224 = 8*403)
    int gid = bid * 256 + threadIdx.x;          // exactly B*LPAD threads
    int b = gid / LPAD;
    int p = gid - b * LPAD;
    int j = p - PADD;
    if (j < 0) j = -j;
    else if (j >= LL) j = 2 * LL - 2 - j;
    int m = j + PADD;
    int tlo = (m - (NFFT - HOP)) >> 9;
    if (tlo < 0) tlo = 0;
    int thi = m >> 9;
    if (thi > TT - 1) thi = TT - 1;
    const double* fb = frames + (size_t)b * TT * NFFT;
    double s = 0.0;
    for (int t = tlo; t <= thi; ++t) s += fb[(size_t)t * NFFT + (m - (t << 9))];
    xp[gid] = s / (double)wsq[m];
}

// ---------------- fused: stft(cur) + recomputed-tpr(prev) + update + istft ----------------
// Momentum state tpr is RECOMPUTED from xp_prev via the identical FFT+untwist
// path that produced it last iteration (bit-identical by determinism), instead
// of being stored/loaded through HBM. first=1 -> tprev = 0 (reference init).
__global__ __launch_bounds__(64) void k_fused(
    const double* __restrict__ xp_cur, const double* __restrict__ xp_prev,
    double* __restrict__ frames_out, const float* __restrict__ mag,
    const double2* __restrict__ tw1024, const double2* __restrict__ tw2048,
    const float* __restrict__ win, int first) {
    __shared__ double2 S[1024];   // current spectrum / work buffer
    __shared__ double2 SP[1024];  // previous spectrum
    const int bx = blockIdx.x;
    const int fid = (bx & 7) * 200 + (bx >> 3);  // XCD swizzle, bijective (1600 = 8*200)
    const int b = fid / TT;
    const int t = fid - b * TT;
    const int tid = threadIdx.x;
    const float2* w2 = reinterpret_cast<const float2*>(win);
    const size_t xoff = (size_t)b * LPAD + (size_t)t * HOP;
    double2 r[16];
    // ---- previous spectrum: windowed xp_prev -> FFT -> SP (skip on first iter)
    if (!first) {
        const double2* xbp = reinterpret_cast<const double2*>(xp_prev + xoff);
#pragma unroll
        for (int j = 0; j < 16; ++j) {
            int k = tid + 64 * j;
            double2 v = xbp[k];
            float2 wv = w2[k];
            r[j] = make_double2(v.x * (double)wv.x, v.y * (double)wv.y);
        }
        fft1024_reg<-1>(r, SP, tw1024, tid);
#pragma unroll
        for (int j = 0; j < 16; ++j) SP[swz(tid + 64 * j)] = r[j];
        // (writes drained by the barriers inside the next FFT before SP is read)
    }
    // ---- current spectrum: windowed xp_cur -> FFT -> S
    {
        const double2* xbc = reinterpret_cast<const double2*>(xp_cur + xoff);
#pragma unroll
        for (int j = 0; j < 16; ++j) {
            int k = tid + 64 * j;
            double2 v = xbc[k];
            float2 wv = w2[k];
            r[j] = make_double2(v.x * (double)wv.x, v.y * (double)wv.y);
        }
    }
    fft1024_reg<-1>(r, S, tw1024, tid);
#pragma unroll
    for (int j = 0; j < 16; ++j) S[swz(tid + 64 * j)] = r[j];
    __syncthreads();
    // ---- middle: untwist both spectra + momentum/phase + new spectrum + pre-twist
    const float* mg = mag + (size_t)fid * FF;
    const double2 zero2 = make_double2(0.0, 0.0);
#pragma unroll
    for (int q = 0; q < 8; ++q) {
        int k = tid + 64 * q;   // [0,512)
        int kp = 1024 - k;
        double2 zk = S[swz(k)];
        double2 zc = S[swz(kp & 1023)];
        double2 wk = tw2048[k];
        double2 Xk = untw(zk, zc, wk);
        double2 XkP = zero2, XpP = zero2;
        double2 zkP, zcP;
        if (!first) {
            zkP = SP[swz(k)];
            zcP = SP[swz(kp & 1023)];
            XkP = untw(zkP, zcP, wk);
        }
        double2 Snew_k = mom_phase(Xk, XkP, mg[k]);
        if (k == 0) {
            double2 X1024 = untw(zk, zk, tw2048[1024]);
            double2 X1024P = zero2;
            double2 z512 = S[swz(512)];
            double2 X512 = untw(z512, z512, tw2048[512]);
            double2 X512P = zero2;
            if (!first) {
                X1024P = untw(zkP, zkP, tw2048[1024]);
                double2 z512P = SP[swz(512)];
                X512P = untw(z512P, z512P, tw2048[512]);
            }
            double2 Snew_1024 = mom_phase(X1024, X1024P, mg[1024]);
            double2 Snew_512  = mom_phase(X512,  X512P,  mg[512]);
            double2 Xk0 = Snew_k;    Xk0.y = 0.0;
            double2 Xc0 = Snew_1024; Xc0.y = 0.0;
            S[swz(0)]   = pretwist(Xk0, Xc0, tw2048[0]);
            S[swz(512)] = pretwist(Snew_512, Snew_512, tw2048[512]);
        } else {
            double2 wp = tw2048[kp];
            double2 Xp = untw(zc, zk, wp);
            if (!first) XpP = untw(zcP, zkP, wp);
            double2 Snew_p = mom_phase(Xp, XpP, mg[kp]);
            S[swz(k)]  = pretwist(Snew_k, Snew_p, wk);
            S[swz(kp)] = pretwist(Snew_p, Snew_k, wp);
        }
    }
    __syncthreads();
    // ---- inverse FFT + window -> frames
#pragma unroll
    for (int j = 0; j < 16; ++j) r[j] = S[swz(tid + 64 * j)];
    fft1024_reg<1>(r, S, tw1024, tid);
    double2* fr = reinterpret_cast<double2*>(frames_out + (size_t)fid * NFFT);
#pragma unroll
    for (int j = 0; j < 16; ++j) {
        int m = tid + 64 * j;
        float2 wv = w2[m];
        fr[m] = make_double2(r[j].x * (1.0 / 1024.0) * (double)wv.x,
                             r[j].y * (1.0 / 1024.0) * (double)wv.y);
    }
}

// ---------------- final: overlap-add -> trimmed fp32 output ----------------
__global__ __launch_bounds__(256) void k_ola_out(
    const double* __restrict__ frames, const float* __restrict__ wsq,
    float* __restrict__ out) {
    int bx = blockIdx.x;
    int bid = (bx & 7) * 399 + (bx >> 3);       // XCD swizzle, bijective (3192 = 8*399)
    int gid = bid * 256 + threadIdx.x;          // exactly B*LL threads
    int b = gid / LL;
    int j = gid - b * LL;
    int m = j + PADD;
    int tlo = (m - (NFFT - HOP)) >> 9;
    if (tlo < 0) tlo = 0;
    int thi = m >> 9;
    if (thi > TT - 1) thi = TT - 1;
    const double* fb = frames + (size_t)b * TT * NFFT;
    double s = 0.0;
    for (int t = tlo; t <= thi; ++t) s += fb[(size_t)t * NFFT + (m - (t << 9))];
    out[gid] = (float)(s / (double)wsq[m]);
}

extern "C" void kernel_launch(void* const* d_in, const int* in_sizes, int n_in,
                              void* d_out, int out_size, void* d_ws, size_t ws_size,
                              hipStream_t stream) {
    if (ws_size < WS_DOUBLES * sizeof(double)) return;  // fail loudly if ws too small
    const float* mag = (const float*)d_in[0];  // (B,T,F) fp32
    double* ws = (double*)d_ws;
    double2* tw1024 = (double2*)(ws + OFF_TW1024);
    double2* tw2048 = (double2*)(ws + OFF_TW2048);
    double* frames  = ws + OFF_FRM;
    double* xp0     = ws + OFF_XP0;
    double* xp1     = ws + OFF_XP1;
    float* win      = (float*)(ws + OFF_WIN32);
    float* wsq      = (float*)(ws + OFF_WSQ32);

    k_init_tables<<<8, 256, 0, stream>>>(tw1024, tw2048, win);
    k_init_wsq<<<LPAD / 256, 256, 0, stream>>>(win, wsq);

    k_istft_first<<<BB * TT, 64, 0, stream>>>(mag, tw1024, tw2048, win, frames);
    for (int it = 0; it < NITER; ++it) {
        double* cur  = (it & 1) ? xp1 : xp0;
        double* prev = (it & 1) ? xp0 : xp1;
        k_ola<<<(BB * LPAD) / 256, 256, 0, stream>>>(frames, wsq, cur);
        k_fused<<<BB * TT, 64, 0, stream>>>(cur, prev, frames, mag,
                                            tw1024, tw2048, win, it == 0 ? 1 : 0);
    }
    k_ola_out<<<(BB * LL) / 256, 256, 0, stream>>>(frames, wsq, (float*)d_out);
}

// Round 21
// 2914.131 us; speedup vs baseline: 1.0024x; 1.0024x over previous
//
#include <hip/hip_runtime.h>
#include <math.h>

// ---------------- problem constants ----------------
constexpr int BB   = 4;
constexpr int TT   = 400;
constexpr int FF   = 1025;
constexpr int NFFT = 2048;
constexpr int HOP  = 512;
constexpr int PADD = 1024;
constexpr int LL   = HOP * (TT - 1);        // 204288
constexpr int LPAD = NFFT + HOP * (TT - 1); // 206336
constexpr int NITER = 60;
constexpr double MOM = 0.99 / 1.99;
constexpr double EPSV = 1e-16;
constexpr double DPI = 3.14159265358979323846;

// workspace offsets in DOUBLES (all even -> 16B alignment)
constexpr size_t OFF_TW1024 = 0;          // 1024 double2 = 2048 d
constexpr size_t OFF_TW2048 = 2048;       // 1025 double2 = 2050 d
constexpr size_t OFF_TPR    = 4098;       // B*T*F double2 = 3280000 d
constexpr size_t OFF_FRM    = 3284098;    // B*T*2048 = 3276800 d
constexpr size_t OFF_XP     = 6560898;    // B*LPAD = 825344 d
constexpr size_t OFF_WIN32  = 7386242;    // f32 window: 2048 f = 1024 d
constexpr size_t OFF_WSQ32  = 7387266;    // f32 wsq divisor: 206336 f = 103168 d
constexpr size_t WS_DOUBLES = 7490434;    // ~59.9 MB

// wave-local LDS fence: single-wave blocks need only lgkmcnt(0) for cross-lane
// LDS visibility (DS ops issue in program order per wave); avoids the
// vmcnt(0) global drain that __syncthreads pays (and that killed prefetch).
#define WFENCE() asm volatile("s_waitcnt lgkmcnt(0)" ::: "memory")

__device__ __forceinline__ double2 cmuld(double2 a, double2 b) {
    return make_double2(a.x * b.x - a.y * b.y, a.x * b.y + a.y * b.x);
}

// LDS layout swizzle (pure permutation of storage slots; injective on [0,1024))
__device__ __forceinline__ int swz(int f) { return f ^ ((f >> 4) & 7); }

// ---------------- numpy SIMD float32 cosine, bit-exact replica ----------------
__device__ __forceinline__ float np_cosf(float x) {
    const float rint_cvt = 0x1.800000p+23f;  // 12582912.0f
    float qf = __builtin_fmaf(x, 0x1.45f306p-1f, rint_cvt) - rint_cvt;
    float r = __builtin_fmaf(qf, -0x1.921fb0p+0f, x);
    r = __builtin_fmaf(qf, -0x1.5110b4p-22f, r);
    r = __builtin_fmaf(qf, -0x1.846988p-48f, r);
    r = __builtin_fmaf(qf, -0x1.8cc966p-73f, r);
    int q = (int)qf + 1;  // cos(x) = sin(x + pi/2)
    float r2 = r * r;
    float cosp = __builtin_fmaf(0x1.98e616p-16f, r2, -0x1.6c06dcp-10f);
    cosp = __builtin_fmaf(cosp, r2, 0x1.55553cp-5f);
    cosp = __builtin_fmaf(cosp, r2, -0x1.000000p-1f);
    cosp = __builtin_fmaf(cosp, r2, 0x1.000000p+0f);
    float sinp = __builtin_fmaf(0x1.7d3bbcp-19f, r2, -0x1.a06bbap-13f);
    sinp = __builtin_fmaf(sinp, r2, 0x1.11119ap-7f);
    sinp = __builtin_fmaf(sinp, r2, -0x1.555548p-3f);
    sinp = sinp * r2;
    sinp = __builtin_fmaf(sinp, r, r);
    float res = (q & 1) ? cosp : sinp;
    return (q & 2) ? -res : res;
}

// ---------------- init kernels ----------------
__global__ void k_init_tables(double2* tw1024, double2* tw2048, float* win) {
    int n = blockIdx.x * blockDim.x + threadIdx.x;
    if (n < 1024) {
        double th = -2.0 * DPI * (double)n / 1024.0;
        double s, c; sincos(th, &s, &c);
        tw1024[n] = make_double2(c, s);
    }
    if (n < 1025) {
        double th = -2.0 * DPI * (double)n / 2048.0;
        double s, c; sincos(th, &s, &c);
        tw2048[n] = make_double2(c, s);
    }
    if (n < 2048) {
        const float TWO_PI_F = 6.283185307179586f;
        float ang = __fdiv_rn(__fmul_rn(TWO_PI_F, (float)n), 2048.0f);
        float c = np_cosf(ang);
        win[n] = __fsub_rn(0.5f, __fmul_rn(0.5f, c));
    }
}

__global__ void k_init_wsq(const float* __restrict__ win, float* __restrict__ wsq) {
    int m = blockIdx.x * blockDim.x + threadIdx.x;
    if (m >= LPAD) return;
    int tlo = (m - (NFFT - HOP)) >> 9;
    if (tlo < 0) tlo = 0;
    int thi = m >> 9;
    if (thi > TT - 1) thi = TT - 1;
    float s = 0.0f;
    for (int t = tlo; t <= thi; ++t) {
        float w = win[m - (t << 9)];
        s = __fadd_rn(s, __fmul_rn(w, w));
    }
    wsq[m] = (s > 1e-11f) ? s : 1.0f;
}

__global__ void k_init_state(double2* __restrict__ tpr) {
    int i = blockIdx.x * blockDim.x + threadIdx.x;
    if (i < BB * TT * FF) tpr[i] = make_double2(0.0, 0.0);
}

// ---------------- radix-4 butterfly (expression-identical to R10) ----------------
template <int DIR, bool TW>
__device__ __forceinline__ void bfly4(double2 a, double2 b, double2 c, double2 d,
                                      double2 w1, double2 w2, double2 w3,
                                      double2& o0, double2& o1, double2& o2, double2& o3) {
    if (TW) {
        if (DIR > 0) { w1.y = -w1.y; w2.y = -w2.y; w3.y = -w3.y; }
        b = cmuld(b, w1);
        c = cmuld(c, w2);
        d = cmuld(d, w3);
    }
    double2 u0 = make_double2(a.x + c.x, a.y + c.y);
    double2 u1 = make_double2(a.x - c.x, a.y - c.y);
    double2 v0 = make_double2(b.x + d.x, b.y + d.y);
    double2 v1 = make_double2(b.x - d.x, b.y - d.y);
    o0 = make_double2(u0.x + v0.x, u0.y + v0.y);
    o2 = make_double2(u0.x - v0.x, u0.y - v0.y);
    if (DIR < 0) {
        o1 = make_double2(u1.x + v1.y, u1.y - v1.x);
        o3 = make_double2(u1.x - v1.y, u1.y + v1.x);
    } else {
        o1 = make_double2(u1.x - v1.y, u1.y + v1.x);
        o3 = make_double2(u1.x + v1.y, u1.y - v1.x);
    }
}

// ---------------- 1024-pt FFT, register-fused, wave-local fences ----------------
// In: r[j] = x[tid + 64*j]. Out: r[j] = X[tid + 64*j]. 64 threads (one wave).
template <int DIR>
__device__ void fft1024_reg(double2 r[16], double2* S, const double2* __restrict__ tw, int tid) {
    const double2 wid = make_double2(1.0, 0.0);
    double2 e[4][4];
#pragma unroll
    for (int m = 0; m < 4; ++m)
        bfly4<DIR, false>(r[m], r[m + 4], r[m + 8], r[m + 12], wid, wid, wid,
                          e[m][0], e[m][1], e[m][2], e[m][3]);
    double2 g[4][4];
#pragma unroll
    for (int r1 = 0; r1 < 4; ++r1) {
        int t1 = r1 << 6;
        bfly4<DIR, true>(e[0][r1], e[1][r1], e[2][r1], e[3][r1],
                         tw[t1 & 1023], tw[(2 * t1) & 1023], tw[(3 * t1) & 1023],
                         g[r1][0], g[r1][1], g[r1][2], g[r1][3]);
    }
#pragma unroll
    for (int r1 = 0; r1 < 4; ++r1)
#pragma unroll
        for (int u = 0; u < 4; ++u)
            S[swz(16 * tid + r1 + 4 * u)] = g[r1][u];
    WFENCE();
    double2 r2[16];
#pragma unroll
    for (int j = 0; j < 16; ++j) r2[j] = S[swz(tid + 64 * j)];
    const int kapp = tid & 15;
    const int aa = tid >> 4;
    double2 h[4][4];
    {
        int t = kapp << 4;
        double2 w1 = tw[t & 1023], w2 = tw[(2 * t) & 1023], w3 = tw[(3 * t) & 1023];
#pragma unroll
        for (int m = 0; m < 4; ++m)
            bfly4<DIR, true>(r2[m], r2[m + 4], r2[m + 8], r2[m + 12], w1, w2, w3,
                             h[m][0], h[m][1], h[m][2], h[m][3]);
    }
    double2 gg[4][4];
#pragma unroll
    for (int u = 0; u < 4; ++u) {
        int t = (kapp + 16 * u) << 2;
        bfly4<DIR, true>(h[0][u], h[1][u], h[2][u], h[3][u],
                         tw[t & 1023], tw[(2 * t) & 1023], tw[(3 * t) & 1023],
                         gg[u][0], gg[u][1], gg[u][2], gg[u][3]);
    }
#pragma unroll
    for (int u = 0; u < 4; ++u)
#pragma unroll
        for (int w = 0; w < 4; ++w)
            S[swz(256 * aa + kapp + 16 * u + 64 * w)] = gg[u][w];
    WFENCE();
    double2 r4[16];
#pragma unroll
    for (int j = 0; j < 16; ++j) r4[j] = S[swz(tid + 64 * j)];
#pragma unroll
    for (int m = 0; m < 4; ++m) {
        int t = tid + 64 * m;
        bfly4<DIR, true>(r4[m], r4[m + 4], r4[m + 8], r4[m + 12],
                         tw[t & 1023], tw[(2 * t) & 1023], tw[(3 * t) & 1023],
                         r[m], r[m + 4], r[m + 8], r[m + 12]);
    }
}

// untwist + momentum/phase update for one output index (expression-identical)
__device__ __forceinline__ double2 phase_step(double2 zk, double2 zc, double2 w,
                                              double2 tp, float mgf, double2* Xk_out) {
    zc.y = -zc.y;
    double2 A = make_double2(0.5 * (zk.x + zc.x), 0.5 * (zk.y + zc.y));
    double2 D = make_double2(zk.x - zc.x, zk.y - zc.y);
    double2 Bv = make_double2(0.5 * D.y, -0.5 * D.x);  // -i*D/2
    double2 wB = cmuld(w, Bv);
    double2 Xk = make_double2(A.x + wB.x, A.y + wB.y);
    double2 a = make_double2(Xk.x - MOM * tp.x, Xk.y - MOM * tp.y);
    double r = sqrt(a.x * a.x + a.y * a.y);
    double d = r + EPSV;
    *Xk_out = Xk;
    double m = (double)mgf;
    return make_double2(m * (a.x / d), m * (a.y / d));
}

// pre-twist producing Z[k] from X[k], X[1024-k] (expression-identical)
__device__ __forceinline__ double2 pretwist(double2 Xk, double2 Xc, double2 w) {
    Xc.y = -Xc.y;
    double2 A = make_double2(0.5 * (Xk.x + Xc.x), 0.5 * (Xk.y + Xc.y));
    double2 D = make_double2(0.5 * (Xk.x - Xc.x), 0.5 * (Xk.y - Xc.y));
    w.y = -w.y;  // conj
    double2 Bv = cmuld(w, D);
    return make_double2(A.x - Bv.y, A.y + Bv.x);  // A + i*B
}

// ---------------- staged in-place FFT (k_istft_first only, runs once) ----------------
template <int DIR>
__device__ void fft1024_w(double2* buf, const double2* __restrict__ tw, int tid) {
#pragma unroll
    for (int s = 0; s < 5; ++s) {
        const int p = 1 << (2 * s);
        double2 o0[4], o1[4], o2[4], o3[4];
        int jj[4];
#pragma unroll
        for (int q = 0; q < 4; ++q) {
            int v = tid + 64 * q;
            int k = v & (p - 1);
            jj[q] = ((v - k) << 2) + k;
            int t1 = k << (8 - 2 * s);
            bfly4<DIR, true>(buf[v], buf[v + 256], buf[v + 512], buf[v + 768],
                             tw[t1 & 1023], tw[(2 * t1) & 1023], tw[(3 * t1) & 1023],
                             o0[q], o1[q], o2[q], o3[q]);
        }
        __syncthreads();
#pragma unroll
        for (int q = 0; q < 4; ++q) {
            buf[jj[q]]         = o0[q];
            buf[jj[q] + p]     = o1[q];
            buf[jj[q] + 2 * p] = o2[q];
            buf[jj[q] + 3 * p] = o3[q];
        }
        __syncthreads();
    }
}

// ---------------- initial frames: istft of (mag, 0), 64-thread ----------------
__global__ __launch_bounds__(64) void k_istft_first(
    const float* __restrict__ mag,
    const double2* __restrict__ tw1024, const double2* __restrict__ tw2048,
    const float* __restrict__ win, double* __restrict__ frames_out) {
    __shared__ double2 S[1025];
    const int fid = blockIdx.x;
    const int tid = threadIdx.x;
    const float* mg = mag + (size_t)fid * FF;
#pragma unroll
    for (int q = 0; q < 8; ++q) {
        int k = tid + 64 * q;  // [0,512)
        double mk = (double)mg[k];
        if (k == 0) {
            double m1024 = (double)mg[1024];
            double m512  = (double)mg[512];
            S[0]   = pretwist(make_double2(mk, 0.0),   make_double2(m1024, 0.0), tw2048[0]);
            S[512] = pretwist(make_double2(m512, 0.0), make_double2(m512, 0.0),  tw2048[512]);
        } else {
            int kp = 1024 - k;
            double mp = (double)mg[kp];
            S[k]  = pretwist(make_double2(mk, 0.0), make_double2(mp, 0.0), tw2048[k]);
            S[kp] = pretwist(make_double2(mp, 0.0), make_double2(mk, 0.0), tw2048[kp]);
        }
    }
    __syncthreads();
    fft1024_w<1>(S, tw1024, tid);
    double2* fr = reinterpret_cast<double2*>(frames_out + (size_t)fid * NFFT);
    const float2* w2 = reinterpret_cast<const float2*>(win);
#pragma unroll
    for (int q = 0; q < 16; ++q) {
        int m = tid + 64 * q;
        double2 z = S[m];
        float2 wv = w2[m];
        fr[m] = make_double2(z.x * (1.0 / 1024.0) * (double)wv.x,
                             z.y * (1.0 / 1024.0) * (double)wv.y);
    }
}

// ---------------- OLA: frames -> normalized reflect-padded signal xp ----------------
__global__ __launch_bounds__(256) void k_ola(
    const double* __restrict__ frames, const float* __restrict__ wsq,
    double* __restrict__ xp) {
    int bx = blockIdx.x;
    int bid = (bx & 7) * 403 + (bx >> 3);       // XCD swizzle, bijective (3224 = 8*403)
    int gid = bid * 256 + threadIdx.x;          // exactly B*LPAD threads
    int b = gid / LPAD;
    int p = gid - b * LPAD;
    int j = p - PADD;
    if (j < 0) j = -j;
    else if (j >= LL) j = 2 * LL - 2 - j;
    int m = j + PADD;
    int tlo = (m - (NFFT - HOP)) >> 9;
    if (tlo < 0) tlo = 0;
    int thi = m >> 9;
    if (thi > TT - 1) thi = TT - 1;
    const double* fb = frames + (size_t)b * TT * NFFT;
    double s = 0.0;
    for (int t = tlo; t <= thi; ++t) s += fb[(size_t)t * NFFT + (m - (t << 9))];
    xp[gid] = s / (double)wsq[m];
}

// ---------------- fused: stft + phase update + istft (1-wave, prefetched tpr) ----------------
__global__ __launch_bounds__(64) void k_fused(
    const double* __restrict__ xp, double* __restrict__ frames_out,
    const float* __restrict__ mag, double2* __restrict__ tpr,
    const double2* __restrict__ tw1024, const double2* __restrict__ tw2048,
    const float* __restrict__ win) {
    __shared__ double2 S[1024];
    const int bx = blockIdx.x;
    const int fid = (bx & 7) * 200 + (bx >> 3);  // XCD swizzle, bijective (1600 = 8*200)
    const int b = fid / TT;
    const int t = fid - b * TT;
    const int tid = threadIdx.x;
    const double2* xb = reinterpret_cast<const double2*>(xp + (size_t)b * LPAD + (size_t)t * HOP);
    const float2* w2 = reinterpret_cast<const float2*>(win);
    // ---- prefetch tpr + mag into registers. Loads stay in flight under the
    // forward FFT because the wave-local fences do NOT drain vmcnt.
    // Lockstep wave: all prefetch loads issue before any middle-phase store,
    // and each thread touches only indices it alone writes -> bit-exact.
    const size_t base = (size_t)fid * FF;
    const float* mg = mag + base;
    double2 tpk[8], tpp[8];
    float mgk[8], mgp[8];
    double2 tp512, tp1024; float mg512f, mg1024f;
#pragma unroll
    for (int q = 0; q < 8; ++q) {
        int k = tid + 64 * q;     // [0,512)
        int kp = 1024 - k;        // (512,1024]
        tpk[q] = tpr[base + k];
        tpp[q] = tpr[base + kp];
        mgk[q] = mg[k];
        mgp[q] = mg[kp];
    }
    if (tid == 0) {
        tp512  = tpr[base + 512];  mg512f  = mg[512];
        tp1024 = tpp[0];           mg1024f = mgp[0];  // kp of q=0 is 1024
    }
    // stage 1: windowed segment -> registers (packed as 1024 complex)
    double2 r[16];
#pragma unroll
    for (int j = 0; j < 16; ++j) {
        int k = tid + 64 * j;
        double2 v = xb[k];
        float2 wv = w2[k];
        r[j] = make_double2(v.x * (double)wv.x, v.y * (double)wv.y);
    }
    fft1024_reg<-1>(r, S, tw1024, tid);  // forward; result in regs
    // publish spectrum to LDS for (k, 1024-k) pair access
#pragma unroll
    for (int j = 0; j < 16; ++j) S[swz(tid + 64 * j)] = r[j];
    WFENCE();
    // middle: untwist + phase update + new spectrum + pre-twist (in place on S)
#pragma unroll
    for (int q = 0; q < 8; ++q) {
        int k = tid + 64 * q;   // [0,512)
        int kp = 1024 - k;
        double2 zk = S[swz(k)];
        double2 zc = S[swz(kp & 1023)];
        double2 wk = tw2048[k];
        double2 Xk;
        double2 Snew_k = phase_step(zk, zc, wk, tpk[q], mgk[q], &Xk);
        tpr[base + k] = Xk;
        if (k == 0) {
            double2 X1024;
            double2 Snew_1024 = phase_step(zk, zk, tw2048[1024], tp1024, mg1024f, &X1024);
            tpr[base + 1024] = X1024;
            double2 z512 = S[swz(512)];
            double2 X512;
            double2 Snew_512 = phase_step(z512, z512, tw2048[512], tp512, mg512f, &X512);
            tpr[base + 512] = X512;
            double2 Xk0 = Snew_k;    Xk0.y = 0.0;
            double2 Xc0 = Snew_1024; Xc0.y = 0.0;
            S[swz(0)]   = pretwist(Xk0, Xc0, tw2048[0]);
            S[swz(512)] = pretwist(Snew_512, Snew_512, tw2048[512]);
        } else {
            double2 wp = tw2048[kp];
            double2 Xp;
            double2 Snew_p = phase_step(zc, zk, wp, tpp[q], mgp[q], &Xp);
            tpr[base + kp] = Xp;
            S[swz(k)]  = pretwist(Snew_k, Snew_p, wk);
            S[swz(kp)] = pretwist(Snew_p, Snew_k, wp);
        }
    }
    WFENCE();
    // inverse FFT: load pre-twisted spectrum to regs, transform, store windowed
#pragma unroll
    for (int j = 0; j < 16; ++j) r[j] = S[swz(tid + 64 * j)];
    fft1024_reg<1>(r, S, tw1024, tid);
    double2* fr = reinterpret_cast<double2*>(frames_out + (size_t)fid * NFFT);
#pragma unroll
    for (int j = 0; j < 16; ++j) {
        int m = tid + 64 * j;
        float2 wv = w2[m];
        fr[m] = make_double2(r[j].x * (1.0 / 1024.0) * (double)wv.x,
                             r[j].y * (1.0 / 1024.0) * (double)wv.y);
    }
}

// ---------------- final: overlap-add -> trimmed fp32 output ----------------
__global__ __launch_bounds__(256) void k_ola_out(
    const double* __restrict__ frames, const float* __restrict__ wsq,
    float* __restrict__ out) {
    int bx = blockIdx.x;
    int bid = (bx & 7) * 399 + (bx >> 3);       // XCD swizzle, bijective (3192 = 8*399)
    int gid = bid * 256 + threadIdx.x;          // exactly B*LL threads
    int b = gid / LL;
    int j = gid - b * LL;
    int m = j + PADD;
    int tlo = (m - (NFFT - HOP)) >> 9;
    if (tlo < 0) tlo = 0;
    int thi = m >> 9;
    if (thi > TT - 1) thi = TT - 1;
    const double* fb = frames + (size_t)b * TT * NFFT;
    double s = 0.0;
    for (int t = tlo; t <= thi; ++t) s += fb[(size_t)t * NFFT + (m - (t << 9))];
    out[gid] = (float)(s / (double)wsq[m]);
}

extern "C" void kernel_launch(void* const* d_in, const int* in_sizes, int n_in,
                              void* d_out, int out_size, void* d_ws, size_t ws_size,
                              hipStream_t stream) {
    if (ws_size < WS_DOUBLES * sizeof(double)) return;  // fail loudly if ws too small
    const float* mag = (const float*)d_in[0];  // (B,T,F) fp32
    double* ws = (double*)d_ws;
    double2* tw1024 = (double2*)(ws + OFF_TW1024);
    double2* tw2048 = (double2*)(ws + OFF_TW2048);
    double2* tprv   = (double2*)(ws + OFF_TPR);
    double* frames  = ws + OFF_FRM;
    double* xp      = ws + OFF_XP;
    float* win      = (float*)(ws + OFF_WIN32);
    float* wsq      = (float*)(ws + OFF_WSQ32);

    k_init_tables<<<8, 256, 0, stream>>>(tw1024, tw2048, win);
    k_init_wsq<<<LPAD / 256, 256, 0, stream>>>(win, wsq);
    k_init_state<<<(BB * TT * FF + 255) / 256, 256, 0, stream>>>(tprv);

    k_istft_first<<<BB * TT, 64, 0, stream>>>(mag, tw1024, tw2048, win, frames);
    for (int it = 0; it < NITER; ++it) {
        k_ola<<<(BB * LPAD) / 256, 256, 0, stream>>>(frames, wsq, xp);
        k_fused<<<BB * TT, 64, 0, stream>>>(xp, frames, mag, tprv,
                                            tw1024, tw2048, win);
    }
    k_ola_out<<<(BB * LL) / 256, 256, 0, stream>>>(frames, wsq, (float*)d_out);
}

// Round 22
// 1770.146 us; speedup vs baseline: 1.6502x; 1.6463x over previous
//
#include <hip/hip_runtime.h>
#include <math.h>

// ---------------- problem constants ----------------
constexpr int BB   = 4;
constexpr int TT   = 400;
constexpr int FF   = 1025;
constexpr int NFFT = 2048;
constexpr int HOP  = 512;
constexpr int PADD = 1024;
constexpr int LL   = HOP * (TT - 1);        // 204288
constexpr int LPAD = NFFT + HOP * (TT - 1); // 206336
constexpr int NITER = 60;
constexpr double MOM = 0.99 / 1.99;
constexpr double EPSV = 1e-16;
constexpr double DPI = 3.14159265358979323846;

// workspace offsets in DOUBLES (all even -> 16B alignment)
constexpr size_t OFF_TW1024 = 0;          // 1024 double2 = 2048 d
constexpr size_t OFF_TW2048 = 2048;       // 1025 double2 = 2050 d
constexpr size_t OFF_TPR    = 4098;       // B*T*F double2 = 3280000 d
constexpr size_t OFF_FRM    = 3284098;    // B*T*2048 = 3276800 d
constexpr size_t OFF_XP     = 6560898;    // B*LPAD = 825344 d
constexpr size_t OFF_WIN32  = 7386242;    // f32 window: 2048 f = 1024 d
constexpr size_t OFF_WSQ32  = 7387266;    // f32 wsq divisor: 206336 f = 103168 d
constexpr size_t WS_DOUBLES = 7490434;    // ~59.9 MB

__device__ __forceinline__ double2 cmuld(double2 a, double2 b) {
    return make_double2(a.x * b.x - a.y * b.y, a.x * b.y + a.y * b.x);
}

// LDS layout swizzle (pure permutation of storage slots; injective on [0,1024))
__device__ __forceinline__ int swz(int f) { return f ^ ((f >> 4) & 7); }

// ---------------- numpy SIMD float32 cosine, bit-exact replica ----------------
__device__ __forceinline__ float np_cosf(float x) {
    const float rint_cvt = 0x1.800000p+23f;  // 12582912.0f
    float qf = __builtin_fmaf(x, 0x1.45f306p-1f, rint_cvt) - rint_cvt;
    float r = __builtin_fmaf(qf, -0x1.921fb0p+0f, x);
    r = __builtin_fmaf(qf, -0x1.5110b4p-22f, r);
    r = __builtin_fmaf(qf, -0x1.846988p-48f, r);
    r = __builtin_fmaf(qf, -0x1.8cc966p-73f, r);
    int q = (int)qf + 1;  // cos(x) = sin(x + pi/2)
    float r2 = r * r;
    float cosp = __builtin_fmaf(0x1.98e616p-16f, r2, -0x1.6c06dcp-10f);
    cosp = __builtin_fmaf(cosp, r2, 0x1.55553cp-5f);
    cosp = __builtin_fmaf(cosp, r2, -0x1.000000p-1f);
    cosp = __builtin_fmaf(cosp, r2, 0x1.000000p+0f);
    float sinp = __builtin_fmaf(0x1.7d3bbcp-19f, r2, -0x1.a06bbap-13f);
    sinp = __builtin_fmaf(sinp, r2, 0x1.11119ap-7f);
    sinp = __builtin_fmaf(sinp, r2, -0x1.555548p-3f);
    sinp = sinp * r2;
    sinp = __builtin_fmaf(sinp, r, r);
    float res = (q & 1) ? cosp : sinp;
    return (q & 2) ? -res : res;
}

// ---------------- init kernels ----------------
__global__ void k_init_tables(double2* tw1024, double2* tw2048, float* win) {
    int n = blockIdx.x * blockDim.x + threadIdx.x;
    if (n < 1024) {
        double th = -2.0 * DPI * (double)n / 1024.0;
        double s, c; sincos(th, &s, &c);
        tw1024[n] = make_double2(c, s);
    }
    if (n < 1025) {
        double th = -2.0 * DPI * (double)n / 2048.0;
        double s, c; sincos(th, &s, &c);
        tw2048[n] = make_double2(c, s);
    }
    if (n < 2048) {
        const float TWO_PI_F = 6.283185307179586f;
        float ang = __fdiv_rn(__fmul_rn(TWO_PI_F, (float)n), 2048.0f);
        float c = np_cosf(ang);
        win[n] = __fsub_rn(0.5f, __fmul_rn(0.5f, c));
    }
}

__global__ void k_init_wsq(const float* __restrict__ win, float* __restrict__ wsq) {
    int m = blockIdx.x * blockDim.x + threadIdx.x;
    if (m >= LPAD) return;
    int tlo = (m - (NFFT - HOP)) >> 9;
    if (tlo < 0) tlo = 0;
    int thi = m >> 9;
    if (thi > TT - 1) thi = TT - 1;
    float s = 0.0f;
    for (int t = tlo; t <= thi; ++t) {
        float w = win[m - (t << 9)];
        s = __fadd_rn(s, __fmul_rn(w, w));
    }
    wsq[m] = (s > 1e-11f) ? s : 1.0f;
}

__global__ void k_init_state(double2* __restrict__ tpr) {
    int i = blockIdx.x * blockDim.x + threadIdx.x;
    if (i < BB * TT * FF) tpr[i] = make_double2(0.0, 0.0);
}

// ---------------- radix-4 butterfly (expression-identical to R10) ----------------
template <int DIR, bool TW>
__device__ __forceinline__ void bfly4(double2 a, double2 b, double2 c, double2 d,
                                      double2 w1, double2 w2, double2 w3,
                                      double2& o0, double2& o1, double2& o2, double2& o3) {
    if (TW) {
        if (DIR > 0) { w1.y = -w1.y; w2.y = -w2.y; w3.y = -w3.y; }
        b = cmuld(b, w1);
        c = cmuld(c, w2);
        d = cmuld(d, w3);
    }
    double2 u0 = make_double2(a.x + c.x, a.y + c.y);
    double2 u1 = make_double2(a.x - c.x, a.y - c.y);
    double2 v0 = make_double2(b.x + d.x, b.y + d.y);
    double2 v1 = make_double2(b.x - d.x, b.y - d.y);
    o0 = make_double2(u0.x + v0.x, u0.y + v0.y);
    o2 = make_double2(u0.x - v0.x, u0.y - v0.y);
    if (DIR < 0) {
        o1 = make_double2(u1.x + v1.y, u1.y - v1.x);
        o3 = make_double2(u1.x - v1.y, u1.y + v1.x);
    } else {
        o1 = make_double2(u1.x - v1.y, u1.y + v1.x);
        o3 = make_double2(u1.x + v1.y, u1.y - v1.x);
    }
}

// ---------------- 1024-pt FFT, same radix-4 Stockham DAG, register-fused ----------------
// In: r[j] = x[tid + 64*j]. Out: r[j] = X[tid + 64*j]. 64 threads.
template <int DIR>
__device__ void fft1024_reg(double2 r[16], double2* S, const double2* __restrict__ tw, int tid) {
    const double2 wid = make_double2(1.0, 0.0);
    double2 e[4][4];
#pragma unroll
    for (int m = 0; m < 4; ++m)
        bfly4<DIR, false>(r[m], r[m + 4], r[m + 8], r[m + 12], wid, wid, wid,
                          e[m][0], e[m][1], e[m][2], e[m][3]);
    double2 g[4][4];
#pragma unroll
    for (int r1 = 0; r1 < 4; ++r1) {
        int t1 = r1 << 6;
        bfly4<DIR, true>(e[0][r1], e[1][r1], e[2][r1], e[3][r1],
                         tw[t1 & 1023], tw[(2 * t1) & 1023], tw[(3 * t1) & 1023],
                         g[r1][0], g[r1][1], g[r1][2], g[r1][3]);
    }
#pragma unroll
    for (int r1 = 0; r1 < 4; ++r1)
#pragma unroll
        for (int u = 0; u < 4; ++u)
            S[swz(16 * tid + r1 + 4 * u)] = g[r1][u];
    __syncthreads();
    double2 r2[16];
#pragma unroll
    for (int j = 0; j < 16; ++j) r2[j] = S[swz(tid + 64 * j)];
    const int kapp = tid & 15;
    const int aa = tid >> 4;
    double2 h[4][4];
    {
        int t = kapp << 4;
        double2 w1 = tw[t & 1023], w2 = tw[(2 * t) & 1023], w3 = tw[(3 * t) & 1023];
#pragma unroll
        for (int m = 0; m < 4; ++m)
            bfly4<DIR, true>(r2[m], r2[m + 4], r2[m + 8], r2[m + 12], w1, w2, w3,
                             h[m][0], h[m][1], h[m][2], h[m][3]);
    }
    double2 gg[4][4];
#pragma unroll
    for (int u = 0; u < 4; ++u) {
        int t = (kapp + 16 * u) << 2;
        bfly4<DIR, true>(h[0][u], h[1][u], h[2][u], h[3][u],
                         tw[t & 1023], tw[(2 * t) & 1023], tw[(3 * t) & 1023],
                         gg[u][0], gg[u][1], gg[u][2], gg[u][3]);
    }
#pragma unroll
    for (int u = 0; u < 4; ++u)
#pragma unroll
        for (int w = 0; w < 4; ++w)
            S[swz(256 * aa + kapp + 16 * u + 64 * w)] = gg[u][w];
    __syncthreads();
    double2 r4[16];
#pragma unroll
    for (int j = 0; j < 16; ++j) r4[j] = S[swz(tid + 64 * j)];
#pragma unroll
    for (int m = 0; m < 4; ++m) {
        int t = tid + 64 * m;
        bfly4<DIR, true>(r4[m], r4[m + 4], r4[m + 8], r4[m + 12],
                         tw[t & 1023], tw[(2 * t) & 1023], tw[(3 * t) & 1023],
                         r[m], r[m + 4], r[m + 8], r[m + 12]);
    }
}

// untwist + momentum/phase update for one output index (expression-identical)
__device__ __forceinline__ double2 phase_step(double2 zk, double2 zc, double2 w,
                                              double2 tp, float mgf, double2* Xk_out) {
    zc.y = -zc.y;
    double2 A = make_double2(0.5 * (zk.x + zc.x), 0.5 * (zk.y + zc.y));
    double2 D = make_double2(zk.x - zc.x, zk.y - zc.y);
    double2 Bv = make_double2(0.5 * D.y, -0.5 * D.x);  // -i*D/2
    double2 wB = cmuld(w, Bv);
    double2 Xk = make_double2(A.x + wB.x, A.y + wB.y);
    double2 a = make_double2(Xk.x - MOM * tp.x, Xk.y - MOM * tp.y);
    double r = sqrt(a.x * a.x + a.y * a.y);
    double d = r + EPSV;
    *Xk_out = Xk;
    double m = (double)mgf;
    return make_double2(m * (a.x / d), m * (a.y / d));
}

// pre-twist producing Z[k] from X[k], X[1024-k] (expression-identical)
__device__ __forceinline__ double2 pretwist(double2 Xk, double2 Xc, double2 w) {
    Xc.y = -Xc.y;
    double2 A = make_double2(0.5 * (Xk.x + Xc.x), 0.5 * (Xk.y + Xc.y));
    double2 D = make_double2(0.5 * (Xk.x - Xc.x), 0.5 * (Xk.y - Xc.y));
    w.y = -w.y;  // conj
    double2 Bv = cmuld(w, D);
    return make_double2(A.x - Bv.y, A.y + Bv.x);  // A + i*B
}

// ---------------- staged in-place FFT (k_istft_first only, runs once) ----------------
template <int DIR>
__device__ void fft1024_w(double2* buf, const double2* __restrict__ tw, int tid) {
#pragma unroll
    for (int s = 0; s < 5; ++s) {
        const int p = 1 << (2 * s);
        double2 o0[4], o1[4], o2[4], o3[4];
        int jj[4];
#pragma unroll
        for (int q = 0; q < 4; ++q) {
            int v = tid + 64 * q;
            int k = v & (p - 1);
            jj[q] = ((v - k) << 2) + k;
            int t1 = k << (8 - 2 * s);
            bfly4<DIR, true>(buf[v], buf[v + 256], buf[v + 512], buf[v + 768],
                             tw[t1 & 1023], tw[(2 * t1) & 1023], tw[(3 * t1) & 1023],
                             o0[q], o1[q], o2[q], o3[q]);
        }
        __syncthreads();
#pragma unroll
        for (int q = 0; q < 4; ++q) {
            buf[jj[q]]         = o0[q];
            buf[jj[q] + p]     = o1[q];
            buf[jj[q] + 2 * p] = o2[q];
            buf[jj[q] + 3 * p] = o3[q];
        }
        __syncthreads();
    }
}

// ---------------- initial frames: istft of (mag, 0), 64-thread ----------------
__global__ __launch_bounds__(64) void k_istft_first(
    const float* __restrict__ mag,
    const double2* __restrict__ tw1024, const double2* __restrict__ tw2048,
    const float* __restrict__ win, double* __restrict__ frames_out) {
    __shared__ double2 S[1025];
    const int fid = blockIdx.x;
    const int tid = threadIdx.x;
    const float* mg = mag + (size_t)fid * FF;
#pragma unroll
    for (int q = 0; q < 8; ++q) {
        int k = tid + 64 * q;  // [0,512)
        double mk = (double)mg[k];
        if (k == 0) {
            double m1024 = (double)mg[1024];
            double m512  = (double)mg[512];
            S[0]   = pretwist(make_double2(mk, 0.0),   make_double2(m1024, 0.0), tw2048[0]);
            S[512] = pretwist(make_double2(m512, 0.0), make_double2(m512, 0.0),  tw2048[512]);
        } else {
            int kp = 1024 - k;
            double mp = (double)mg[kp];
            S[k]  = pretwist(make_double2(mk, 0.0), make_double2(mp, 0.0), tw2048[k]);
            S[kp] = pretwist(make_double2(mp, 0.0), make_double2(mk, 0.0), tw2048[kp]);
        }
    }
    __syncthreads();
    fft1024_w<1>(S, tw1024, tid);
    double2* fr = reinterpret_cast<double2*>(frames_out + (size_t)fid * NFFT);
    const float2* w2 = reinterpret_cast<const float2*>(win);
#pragma unroll
    for (int q = 0; q < 16; ++q) {
        int m = tid + 64 * q;
        double2 z = S[m];
        float2 wv = w2[m];
        fr[m] = make_double2(z.x * (1.0 / 1024.0) * (double)wv.x,
                             z.y * (1.0 / 1024.0) * (double)wv.y);
    }
}

// ---------------- OLA: frames -> normalized reflect-padded signal xp ----------------
__global__ __launch_bounds__(256) void k_ola(
    const double* __restrict__ frames, const float* __restrict__ wsq,
    double* __restrict__ xp) {
    int bx = blockIdx.x;
    int bid = (bx & 7) * 403 + (bx >> 3);       // XCD swizzle, bijective (3224 = 8*403)
    int gid = bid * 256 + threadIdx.x;          // exactly B*LPAD threads
    int b = gid / LPAD;
    int p = gid - b * LPAD;
    int j = p - PADD;
    if (j < 0) j = -j;
    else if (j >= LL) j = 2 * LL - 2 - j;
    int m = j + PADD;
    int tlo = (m - (NFFT - HOP)) >> 9;
    if (tlo < 0) tlo = 0;
    int thi = m >> 9;
    if (thi > TT - 1) thi = TT - 1;
    const double* fb = frames + (size_t)b * TT * NFFT;
    double s = 0.0;
    for (int t = tlo; t <= thi; ++t) s += fb[(size_t)t * NFFT + (m - (t << 9))];
    xp[gid] = s / (double)wsq[m];
}

// ---------------- fused: stft + phase update + istft -> frames (64-thread) ----------------
__global__ __launch_bounds__(64) void k_fused(
    const double* __restrict__ xp, double* __restrict__ frames_out,
    const float* __restrict__ mag, double2* __restrict__ tpr,
    const double2* __restrict__ tw1024, const double2* __restrict__ tw2048,
    const float* __restrict__ win) {
    __shared__ double2 S[1024];
    const int bx = blockIdx.x;
    const int fid = (bx & 7) * 200 + (bx >> 3);  // XCD swizzle, bijective (1600 = 8*200)
    const int b = fid / TT;
    const int t = fid - b * TT;
    const int tid = threadIdx.x;
    const double2* xb = reinterpret_cast<const double2*>(xp + (size_t)b * LPAD + (size_t)t * HOP);
    const float2* w2 = reinterpret_cast<const float2*>(win);
    // stage 1: windowed segment -> registers (packed as 1024 complex)
    double2 r[16];
#pragma unroll
    for (int j = 0; j < 16; ++j) {
        int k = tid + 64 * j;
        double2 v = xb[k];
        float2 wv = w2[k];
        r[j] = make_double2(v.x * (double)wv.x, v.y * (double)wv.y);
    }
    fft1024_reg<-1>(r, S, tw1024, tid);  // forward; result in regs
    // publish spectrum to LDS for (k, 1024-k) pair access
#pragma unroll
    for (int j = 0; j < 16; ++j) S[swz(tid + 64 * j)] = r[j];
    __syncthreads();
    // middle: untwist + phase update + new spectrum + pre-twist (in place on S)
    size_t base = (size_t)fid * FF;
    const float* mg = mag + base;
#pragma unroll
    for (int q = 0; q < 8; ++q) {
        int k = tid + 64 * q;   // [0,512)
        int kp = 1024 - k;
        double2 zk = S[swz(k)];
        double2 zc = S[swz(kp & 1023)];
        double2 wk = tw2048[k];
        double2 Xk;
        double2 Snew_k = phase_step(zk, zc, wk, tpr[base + k], mg[k], &Xk);
        tpr[base + k] = Xk;
        if (k == 0) {
            double2 X1024;
            double2 Snew_1024 = phase_step(zk, zk, tw2048[1024], tpr[base + 1024], mg[1024], &X1024);
            tpr[base + 1024] = X1024;
            double2 z512 = S[swz(512)];
            double2 X512;
            double2 Snew_512 = phase_step(z512, z512, tw2048[512], tpr[base + 512], mg[512], &X512);
            tpr[base + 512] = X512;
            double2 Xk0 = Snew_k;    Xk0.y = 0.0;
            double2 Xc0 = Snew_1024; Xc0.y = 0.0;
            S[swz(0)]   = pretwist(Xk0, Xc0, tw2048[0]);
            S[swz(512)] = pretwist(Snew_512, Snew_512, tw2048[512]);
        } else {
            double2 wp = tw2048[kp];
            double2 Xp;
            double2 Snew_p = phase_step(zc, zk, wp, tpr[base + kp], mg[kp], &Xp);
            tpr[base + kp] = Xp;
            S[swz(k)]  = pretwist(Snew_k, Snew_p, wk);
            S[swz(kp)] = pretwist(Snew_p, Snew_k, wp);
        }
    }
    __syncthreads();
    // inverse FFT: load pre-twisted spectrum to regs, transform, store windowed
#pragma unroll
    for (int j = 0; j < 16; ++j) r[j] = S[swz(tid + 64 * j)];
    fft1024_reg<1>(r, S, tw1024, tid);
    double2* fr = reinterpret_cast<double2*>(frames_out + (size_t)fid * NFFT);
#pragma unroll
    for (int j = 0; j < 16; ++j) {
        int m = tid + 64 * j;
        float2 wv = w2[m];
        fr[m] = make_double2(r[j].x * (1.0 / 1024.0) * (double)wv.x,
                             r[j].y * (1.0 / 1024.0) * (double)wv.y);
    }
}

// ---------------- final: overlap-add -> trimmed fp32 output ----------------
__global__ __launch_bounds__(256) void k_ola_out(
    const double* __restrict__ frames, const float* __restrict__ wsq,
    float* __restrict__ out) {
    int bx = blockIdx.x;
    int bid = (bx & 7) * 399 + (bx >> 3);       // XCD swizzle, bijective (3192 = 8*399)
    int gid = bid * 256 + threadIdx.x;          // exactly B*LL threads
    int b = gid / LL;
    int j = gid - b * LL;
    int m = j + PADD;
    int tlo = (m - (NFFT - HOP)) >> 9;
    if (tlo < 0) tlo = 0;
    int thi = m >> 9;
    if (thi > TT - 1) thi = TT - 1;
    const double* fb = frames + (size_t)b * TT * NFFT;
    double s = 0.0;
    for (int t = tlo; t <= thi; ++t) s += fb[(size_t)t * NFFT + (m - (t << 9))];
    out[gid] = (float)(s / (double)wsq[m]);
}

extern "C" void kernel_launch(void* const* d_in, const int* in_sizes, int n_in,
                              void* d_out, int out_size, void* d_ws, size_t ws_size,
                              hipStream_t stream) {
    if (ws_size < WS_DOUBLES * sizeof(double)) return;  // fail loudly if ws too small
    const float* mag = (const float*)d_in[0];  // (B,T,F) fp32
    double* ws = (double*)d_ws;
    double2* tw1024 = (double2*)(ws + OFF_TW1024);
    double2* tw2048 = (double2*)(ws + OFF_TW2048);
    double2* tprv   = (double2*)(ws + OFF_TPR);
    double* frames  = ws + OFF_FRM;
    double* xp      = ws + OFF_XP;
    float* win      = (float*)(ws + OFF_WIN32);
    float* wsq      = (float*)(ws + OFF_WSQ32);

    k_init_tables<<<8, 256, 0, stream>>>(tw1024, tw2048, win);
    k_init_wsq<<<LPAD / 256, 256, 0, stream>>>(win, wsq);
    k_init_state<<<(BB * TT * FF + 255) / 256, 256, 0, stream>>>(tprv);

    k_istft_first<<<BB * TT, 64, 0, stream>>>(mag, tw1024, tw2048, win, frames);
    for (int it = 0; it < NITER; ++it) {
        k_ola<<<(BB * LPAD) / 256, 256, 0, stream>>>(frames, wsq, xp);
        k_fused<<<BB * TT, 64, 0, stream>>>(xp, frames, mag, tprv,
                                            tw1024, tw2048, win);
    }
    k_ola_out<<<(BB * LL) / 256, 256, 0, stream>>>(frames, wsq, (float*)d_out);
}